// Round 1
// baseline (1691.005 us; speedup 1.0000x reference)
//
#include <hip/hip_runtime.h>
#include <math.h>

#define B_ 8
#define S_ 2048
#define F_ 1024
#define U_ 256
#define M_ (B_ * S_)   // 16384 rows

// ---------------------------------------------------------------------------
// Phase 1: out = tanh(x @ W) for W in {Wq, Wk, Wv}, fp32.
// Tile: BM=128, BN=64, BK=16; 256 threads; 8x4 micro-tile per thread.
// Grid: (M/128, 256/64, 3). Results to ws as [3][M][U] fp32 (48 MiB).
// ---------------------------------------------------------------------------
__global__ __launch_bounds__(256) void proj_tanh_kernel(
    const float* __restrict__ x,
    const float* __restrict__ Wq,
    const float* __restrict__ Wk,
    const float* __restrict__ Wv,
    float* __restrict__ qkv)
{
    const int bm   = blockIdx.x;
    const int bn   = blockIdx.y;
    const int wsel = blockIdx.z;
    const float* __restrict__ W = (wsel == 0) ? Wq : (wsel == 1) ? Wk : Wv;
    float* __restrict__ out = qkv + (size_t)wsel * M_ * U_;

    __shared__ float As[16][128];   // As[k][m]
    __shared__ float Bs[16][64];    // Bs[k][n]

    const int tid = threadIdx.x;
    const int ty = tid >> 4;        // 0..15 -> rows ty*8..+7
    const int tx = tid & 15;        // 0..15 -> cols tx*4..+3
    const int row0 = bm * 128;
    const int col0 = bn * 64;

    float acc[8][4];
    #pragma unroll
    for (int i = 0; i < 8; ++i)
        #pragma unroll
        for (int j = 0; j < 4; ++j) acc[i][j] = 0.f;

    for (int k0 = 0; k0 < F_; k0 += 16) {
        // stage A tile: 128 rows x 16 k = 512 float4
        #pragma unroll
        for (int i = 0; i < 2; ++i) {
            int f4 = tid + i * 256;
            int r = f4 >> 2, k4 = f4 & 3;
            const float4 v = *reinterpret_cast<const float4*>(
                x + (size_t)(row0 + r) * F_ + k0 + k4 * 4);
            As[k4 * 4 + 0][r] = v.x; As[k4 * 4 + 1][r] = v.y;
            As[k4 * 4 + 2][r] = v.z; As[k4 * 4 + 3][r] = v.w;
        }
        // stage B tile: 16 rows x 64 cols = 256 float4
        {
            int kr = tid >> 4, c4 = tid & 15;
            const float4 v = *reinterpret_cast<const float4*>(
                W + (size_t)(k0 + kr) * U_ + col0 + c4 * 4);
            *reinterpret_cast<float4*>(&Bs[kr][c4 * 4]) = v;
        }
        __syncthreads();
        #pragma unroll
        for (int k = 0; k < 16; ++k) {
            float a[8], b[4];
            #pragma unroll
            for (int i = 0; i < 8; ++i) a[i] = As[k][ty * 8 + i];
            #pragma unroll
            for (int j = 0; j < 4; ++j) b[j] = Bs[k][tx * 4 + j];
            #pragma unroll
            for (int i = 0; i < 8; ++i)
                #pragma unroll
                for (int j = 0; j < 4; ++j)
                    acc[i][j] = fmaf(a[i], b[j], acc[i][j]);
        }
        __syncthreads();
    }
    #pragma unroll
    for (int i = 0; i < 8; ++i) {
        float4 v;
        v.x = tanhf(acc[i][0]); v.y = tanhf(acc[i][1]);
        v.z = tanhf(acc[i][2]); v.w = tanhf(acc[i][3]);
        *reinterpret_cast<float4*>(
            out + (size_t)(row0 + ty * 8 + i) * U_ + col0 + tx * 4) = v;
    }
}

// ---------------------------------------------------------------------------
// Phase 2: flash attention, fp32. Block = 32 query rows of one batch.
// Iterate 64 key tiles of 32. Online softmax (running m,l in LDS).
// 256 threads. Score mapping: (sy,sx) 16x16 -> 2x2 scores.
// Acc/PV mapping: (ar,ac) 8x32 -> 4 rows x 8 cols of acc (32 regs).
// LDS: Qs 32K + Ks 4K + Vs 32K + Pt 4K + stats ~ 74 KB -> 2 blocks/CU.
// ---------------------------------------------------------------------------
__global__ __launch_bounds__(256) void attn_kernel(
    const float* __restrict__ qkv, float* __restrict__ out)
{
    const int qb = blockIdx.x;   // 0..63
    const int b  = blockIdx.y;   // 0..7
    const float* __restrict__ Q = qkv;
    const float* __restrict__ K = qkv + (size_t)M_ * U_;
    const float* __restrict__ V = qkv + (size_t)2 * M_ * U_;

    __shared__ float Qs[U_][32];   // Qs[u][qrow]
    __shared__ float Ks[32][32];   // Ks[uu][kcol]  (one 32-wide u chunk)
    __shared__ float Vs[32][U_];   // Vs[k][u]
    __shared__ float Pt[32][32];   // Pt[kcol][qrow]
    __shared__ float m_s[32], l_s[32], sf_s[32];

    const int tid = threadIdx.x;
    const int sy = tid >> 4, sx = tid & 15;   // scores: rows 2sy+i, cols 2sx+j
    const int ar = tid >> 5, ac = tid & 31;   // acc: rows 4ar+i, cols 8ac+j

    const int row0  = b * S_ + qb * 32;   // absolute Q/out row
    const int kbase = b * S_;

    // stage Q tile transposed: 32 rows x 256 u = 2048 float4
    #pragma unroll
    for (int i = 0; i < 8; ++i) {
        int f4 = tid + i * 256;
        int r = f4 >> 6, u4 = f4 & 63;
        float4 v = *reinterpret_cast<const float4*>(
            Q + (size_t)(row0 + r) * U_ + u4 * 4);
        Qs[u4 * 4 + 0][r] = v.x; Qs[u4 * 4 + 1][r] = v.y;
        Qs[u4 * 4 + 2][r] = v.z; Qs[u4 * 4 + 3][r] = v.w;
    }
    if (tid < 32) { m_s[tid] = -INFINITY; l_s[tid] = 0.f; }

    float acc[4][8];
    #pragma unroll
    for (int i = 0; i < 4; ++i)
        #pragma unroll
        for (int j = 0; j < 8; ++j) acc[i][j] = 0.f;

    for (int t0 = 0; t0 < S_; t0 += 32) {
        __syncthreads();   // previous PV done -> safe to overwrite Vs
        // stage V tile (natural layout): 32 rows x 256 = 2048 float4
        #pragma unroll
        for (int i = 0; i < 8; ++i) {
            int f4 = tid + i * 256;
            int r = f4 >> 6, c4 = f4 & 63;
            *reinterpret_cast<float4*>(&Vs[r][c4 * 4]) =
                *reinterpret_cast<const float4*>(
                    V + (size_t)(kbase + t0 + r) * U_ + c4 * 4);
        }

        float s00 = 0.f, s01 = 0.f, s10 = 0.f, s11 = 0.f;
        for (int uc = 0; uc < 8; ++uc) {
            __syncthreads();   // previous chunk's compute done
            {  // stage K chunk transposed: 32 keys x 32 u
                int j = tid >> 3, u4 = tid & 7;
                float4 v = *reinterpret_cast<const float4*>(
                    K + (size_t)(kbase + t0 + j) * U_ + uc * 32 + u4 * 4);
                Ks[u4 * 4 + 0][j] = v.x; Ks[u4 * 4 + 1][j] = v.y;
                Ks[u4 * 4 + 2][j] = v.z; Ks[u4 * 4 + 3][j] = v.w;
            }
            __syncthreads();
            const int ub = uc * 32;
            #pragma unroll
            for (int uu = 0; uu < 32; ++uu) {
                float q0 = Qs[ub + uu][2 * sy];
                float q1 = Qs[ub + uu][2 * sy + 1];
                float k0 = Ks[uu][2 * sx];
                float k1 = Ks[uu][2 * sx + 1];
                s00 = fmaf(q0, k0, s00); s01 = fmaf(q0, k1, s01);
                s10 = fmaf(q1, k0, s10); s11 = fmaf(q1, k1, s11);
            }
        }
        const float scale = 0.03125f;   // 1/sqrt(F=1024) -- NOT 1/sqrt(U)!
        s00 *= scale; s01 *= scale; s10 *= scale; s11 *= scale;

        // online softmax for rows 2sy, 2sy+1 (16 lanes per row group, in-wave)
        float r0 = fmaxf(s00, s01), r1 = fmaxf(s10, s11);
        #pragma unroll
        for (int m = 1; m < 16; m <<= 1) {
            r0 = fmaxf(r0, __shfl_xor(r0, m));
            r1 = fmaxf(r1, __shfl_xor(r1, m));
        }
        float mo0 = m_s[2 * sy], mo1 = m_s[2 * sy + 1];
        float mn0 = fmaxf(mo0, r0), mn1 = fmaxf(mo1, r1);
        float p00 = expf(s00 - mn0), p01 = expf(s01 - mn0);
        float p10 = expf(s10 - mn1), p11 = expf(s11 - mn1);
        float su0 = p00 + p01, su1 = p10 + p11;
        #pragma unroll
        for (int m = 1; m < 16; m <<= 1) {
            su0 += __shfl_xor(su0, m);
            su1 += __shfl_xor(su1, m);
        }
        float sc0 = expf(mo0 - mn0), sc1 = expf(mo1 - mn1);  // exp(-inf)=0 on tile 0
        if (sx == 0) {
            m_s[2 * sy] = mn0;       m_s[2 * sy + 1] = mn1;
            sf_s[2 * sy] = sc0;      sf_s[2 * sy + 1] = sc1;
            l_s[2 * sy] = l_s[2 * sy] * sc0 + su0;
            l_s[2 * sy + 1] = l_s[2 * sy + 1] * sc1 + su1;
        }
        Pt[2 * sx + 0][2 * sy + 0] = p00;
        Pt[2 * sx + 1][2 * sy + 0] = p01;
        Pt[2 * sx + 0][2 * sy + 1] = p10;
        Pt[2 * sx + 1][2 * sy + 1] = p11;
        __syncthreads();   // Pt, sf_s, Vs all visible

        // rescale acc and accumulate P @ V
        float f0 = sf_s[4 * ar + 0], f1 = sf_s[4 * ar + 1];
        float f2 = sf_s[4 * ar + 2], f3 = sf_s[4 * ar + 3];
        #pragma unroll
        for (int j = 0; j < 8; ++j) {
            acc[0][j] *= f0; acc[1][j] *= f1;
            acc[2][j] *= f2; acc[3][j] *= f3;
        }
        #pragma unroll
        for (int k = 0; k < 32; ++k) {
            float4 pv = *reinterpret_cast<const float4*>(&Pt[k][4 * ar]);
            float4 v0 = *reinterpret_cast<const float4*>(&Vs[k][8 * ac]);
            float4 v1 = *reinterpret_cast<const float4*>(&Vs[k][8 * ac + 4]);
            float pr[4] = {pv.x, pv.y, pv.z, pv.w};
            float vr[8] = {v0.x, v0.y, v0.z, v0.w, v1.x, v1.y, v1.z, v1.w};
            #pragma unroll
            for (int i = 0; i < 4; ++i)
                #pragma unroll
                for (int j = 0; j < 8; ++j)
                    acc[i][j] = fmaf(pr[i], vr[j], acc[i][j]);
        }
    }

    // epilogue: out = acc / l
    float li[4];
    #pragma unroll
    for (int i = 0; i < 4; ++i) li[i] = 1.0f / l_s[4 * ar + i];
    #pragma unroll
    for (int i = 0; i < 4; ++i) {
        float4 o0, o1;
        o0.x = acc[i][0] * li[i]; o0.y = acc[i][1] * li[i];
        o0.z = acc[i][2] * li[i]; o0.w = acc[i][3] * li[i];
        o1.x = acc[i][4] * li[i]; o1.y = acc[i][5] * li[i];
        o1.z = acc[i][6] * li[i]; o1.w = acc[i][7] * li[i];
        float* dst = out + (size_t)(row0 + 4 * ar + i) * U_ + 8 * ac;
        *reinterpret_cast<float4*>(dst)     = o0;
        *reinterpret_cast<float4*>(dst + 4) = o1;
    }
}

extern "C" void kernel_launch(void* const* d_in, const int* in_sizes, int n_in,
                              void* d_out, int out_size, void* d_ws, size_t ws_size,
                              hipStream_t stream)
{
    (void)in_sizes; (void)n_in; (void)out_size; (void)ws_size;
    const float* x  = (const float*)d_in[0];
    const float* Wq = (const float*)d_in[1];
    const float* Wk = (const float*)d_in[2];
    const float* Wv = (const float*)d_in[3];
    float* out = (float*)d_out;
    float* qkv = (float*)d_ws;   // needs 3 * 16384 * 256 * 4 B = 48 MiB scratch

    dim3 g1(M_ / 128, U_ / 64, 3);
    proj_tanh_kernel<<<g1, 256, 0, stream>>>(x, Wq, Wk, Wv, qkv);

    dim3 g2(S_ / 32, B_);
    attn_kernel<<<g2, 256, 0, stream>>>(qkv, out);
}

// Round 2
// 577.960 us; speedup vs baseline: 2.9258x; 2.9258x over previous
//
#include <hip/hip_runtime.h>
#include <math.h>

#define B_ 8
#define S_ 2048
#define F_ 1024
#define U_ 256
#define M_ (B_ * S_)   // 16384 rows

typedef __attribute__((ext_vector_type(8))) short bf16x8;
typedef __attribute__((ext_vector_type(4))) float f32x4;
typedef unsigned short ushort_t;

__device__ __forceinline__ unsigned short f2bf(float x) {
    unsigned u = __builtin_bit_cast(unsigned, x);
    unsigned r = (u + 0x7fffu + ((u >> 16) & 1u)) >> 16;   // RNE
    return (unsigned short)r;
}
__device__ __forceinline__ float bf2f(unsigned short b) {
    return __builtin_bit_cast(float, ((unsigned)b) << 16);
}
__device__ __forceinline__ void gload16(const void* g, void* l) {
    __builtin_amdgcn_global_load_lds(
        (const __attribute__((address_space(1))) unsigned int*)g,
        (__attribute__((address_space(3))) unsigned int*)l, 16, 0, 0);
}
__device__ __forceinline__ f32x4 zero4() {
    f32x4 v; v[0] = 0.f; v[1] = 0.f; v[2] = 0.f; v[3] = 0.f; return v;
}

// ---------------------------------------------------------------------------
// Phase 1: t = tanh(x @ W); emit Q,K as bf16 hi/lo [M][U]; V transposed
// hi/lo as [B][U][S]. fp32 GEMM core identical to round-1 (verified).
// ---------------------------------------------------------------------------
__global__ __launch_bounds__(256) void proj_tanh_kernel(
    const float* __restrict__ x,
    const float* __restrict__ Wq,
    const float* __restrict__ Wk,
    const float* __restrict__ Wv,
    ushort_t* __restrict__ qhi, ushort_t* __restrict__ qlo,
    ushort_t* __restrict__ khi, ushort_t* __restrict__ klo,
    ushort_t* __restrict__ vthi, ushort_t* __restrict__ vtlo)
{
    const int bm   = blockIdx.x;
    const int bn   = blockIdx.y;
    const int wsel = blockIdx.z;
    const float* __restrict__ W = (wsel == 0) ? Wq : (wsel == 1) ? Wk : Wv;

    __shared__ float As[16][128];   // As[k][m]
    __shared__ float Bs[16][64];    // Bs[k][n]

    const int tid = threadIdx.x;
    const int ty = tid >> 4;        // rows ty*8..+7
    const int tx = tid & 15;        // cols tx*4..+3
    const int row0 = bm * 128;
    const int col0 = bn * 64;

    float acc[8][4];
    #pragma unroll
    for (int i = 0; i < 8; ++i)
        #pragma unroll
        for (int j = 0; j < 4; ++j) acc[i][j] = 0.f;

    for (int k0 = 0; k0 < F_; k0 += 16) {
        #pragma unroll
        for (int i = 0; i < 2; ++i) {
            int f4 = tid + i * 256;
            int r = f4 >> 2, k4 = f4 & 3;
            const float4 v = *reinterpret_cast<const float4*>(
                x + (size_t)(row0 + r) * F_ + k0 + k4 * 4);
            As[k4 * 4 + 0][r] = v.x; As[k4 * 4 + 1][r] = v.y;
            As[k4 * 4 + 2][r] = v.z; As[k4 * 4 + 3][r] = v.w;
        }
        {
            int kr = tid >> 4, c4 = tid & 15;
            const float4 v = *reinterpret_cast<const float4*>(
                W + (size_t)(k0 + kr) * U_ + col0 + c4 * 4);
            *reinterpret_cast<float4*>(&Bs[kr][c4 * 4]) = v;
        }
        __syncthreads();
        #pragma unroll
        for (int k = 0; k < 16; ++k) {
            float a[8], bb[4];
            #pragma unroll
            for (int i = 0; i < 8; ++i) a[i] = As[k][ty * 8 + i];
            #pragma unroll
            for (int j = 0; j < 4; ++j) bb[j] = Bs[k][tx * 4 + j];
            #pragma unroll
            for (int i = 0; i < 8; ++i)
                #pragma unroll
                for (int j = 0; j < 4; ++j)
                    acc[i][j] = fmaf(a[i], bb[j], acc[i][j]);
        }
        __syncthreads();
    }

    // epilogue: tanh + split to bf16 hi/lo
    ushort_t bh[8][4], bl[8][4];
    #pragma unroll
    for (int i = 0; i < 8; ++i)
        #pragma unroll
        for (int j = 0; j < 4; ++j) {
            float t = tanhf(acc[i][j]);
            ushort_t h = f2bf(t);
            bh[i][j] = h;
            bl[i][j] = f2bf(t - bf2f(h));
        }

    if (wsel < 2) {
        ushort_t* hi = (wsel == 0) ? qhi : khi;
        ushort_t* lo = (wsel == 0) ? qlo : klo;
        #pragma unroll
        for (int i = 0; i < 8; ++i) {
            size_t off = (size_t)(row0 + ty * 8 + i) * U_ + col0 + tx * 4;
            ushort4 hv, lv;
            hv.x = bh[i][0]; hv.y = bh[i][1]; hv.z = bh[i][2]; hv.w = bh[i][3];
            lv.x = bl[i][0]; lv.y = bl[i][1]; lv.z = bl[i][2]; lv.w = bl[i][3];
            *reinterpret_cast<ushort4*>(hi + off) = hv;
            *reinterpret_cast<ushort4*>(lo + off) = lv;
        }
    } else {
        const int b  = row0 >> 11;              // 128-row tiles never straddle batches
        const int s0 = (row0 & 2047) + ty * 8;
        #pragma unroll
        for (int j = 0; j < 4; ++j) {
            const int u = col0 + tx * 4 + j;
            bf16x8 hv, lv;
            #pragma unroll
            for (int i = 0; i < 8; ++i) { hv[i] = (short)bh[i][j]; lv[i] = (short)bl[i][j]; }
            size_t off = ((size_t)b * U_ + u) * S_ + s0;
            *reinterpret_cast<bf16x8*>(vthi + off) = hv;
            *reinterpret_cast<bf16x8*>(vtlo + off) = lv;
        }
    }
}

// ---------------------------------------------------------------------------
// Phase 2: flash attention, split-bf16 MFMA (3-pass == fp32 precision).
// 256 blocks (XCD-swizzled so each XCD owns one batch), 4 waves x 16 q-rows.
// KT=32 keys/tile, 64 tiles, double-buffered K/V staged via global_load_lds
// (K: XOR-swizzled via pre-swizzled global source; V: +8 pad rows).
// S^T = mfma(K, Q^T) so softmax is lane-local + 2 shuffles; P goes through a
// conflict-free wave-private LDS buffer shaped as the PV A-fragment.
// ---------------------------------------------------------------------------
__global__ __launch_bounds__(256, 1) void attn_mfma_kernel(
    const ushort_t* __restrict__ qhi, const ushort_t* __restrict__ qlo,
    const ushort_t* __restrict__ khi, const ushort_t* __restrict__ klo,
    const ushort_t* __restrict__ vthi, const ushort_t* __restrict__ vtlo,
    float* __restrict__ out)
{
    __shared__ ushort_t Kbuf[2][2][32 * 256];   // [dbuf][half][key][u] swizzled (64 KB)
    __shared__ ushort_t Vbuf[2][2][256 * 40];   // [dbuf][half][u][32+8pad]   (80 KB)
    __shared__ ushort_t Pbuf[2][4][512];        // [half][wave][kg][q][8]      (8 KB)

    const int tid = threadIdx.x;
    const int l  = tid & 63, w = tid >> 6;
    const int kq = l & 15,  g = l >> 4;

    // XCD swizzle: all 32 q-tiles of one batch land on one XCD (K/V L2-resident)
    const int logical = (blockIdx.x & 7) * 32 + (blockIdx.x >> 3);
    const int b  = logical >> 5;
    const int qb = logical & 31;
    const int qrow0 = b * S_ + qb * 64 + w * 16;

    // preload Q fragments (B-operand: n = lane&15 -> q, k = u = g*8+j)
    bf16x8 qh[8], qlv[8];
    {
        const ushort_t* qbh = qhi + (size_t)(qrow0 + kq) * U_;
        const ushort_t* qbl = qlo + (size_t)(qrow0 + kq) * U_;
        #pragma unroll
        for (int us = 0; us < 8; ++us) {
            qh[us]  = *reinterpret_cast<const bf16x8*>(qbh + us * 32 + g * 8);
            qlv[us] = *reinterpret_cast<const bf16x8*>(qbl + us * 32 + g * 8);
        }
    }

    f32x4 O[16];
    #pragma unroll
    for (int nt = 0; nt < 16; ++nt) O[nt] = zero4();
    float m_run = -INFINITY, l_run = 0.f;

    auto stage = [&](int buf, int k0) {
        // K: 1024 16B-chunks per half; wave w: chunks w*256 + i*64 + lane
        #pragma unroll
        for (int i = 0; i < 4; ++i) {
            int c = w * 256 + i * 64 + l;
            int key = c >> 5, uc = c & 31;
            int ucs = uc ^ (key & 7);                       // pre-swizzled source
            size_t so = (size_t)(b * S_ + k0 + key) * U_ + ucs * 8;
            gload16(khi + so, &Kbuf[buf][0][(w * 256 + i * 64) * 8]);
            gload16(klo + so, &Kbuf[buf][1][(w * 256 + i * 64) * 8]);
        }
        // V: 1280 chunks per half (rows of 5 chunks: 4 data + 1 pad)
        #pragma unroll
        for (int i = 0; i < 5; ++i) {
            int c = w * 320 + i * 64 + l;
            int u = (c * 52429) >> 18;                      // c / 5
            int kc = c - u * 5;
            size_t so = ((size_t)b * U_ + u) * S_ + k0 + kc * 8;
            const ushort_t* sh = (kc < 4) ? (vthi + so) : vthi;
            const ushort_t* sl = (kc < 4) ? (vtlo + so) : vtlo;
            gload16(sh, &Vbuf[buf][0][(w * 320 + i * 64) * 8]);
            gload16(sl, &Vbuf[buf][1][(w * 320 + i * 64) * 8]);
        }
    };

    stage(0, 0);
    asm volatile("s_waitcnt vmcnt(0)" ::: "memory");
    __builtin_amdgcn_s_barrier();

    const float scale = 0.03125f;   // 1/sqrt(F=1024)

    for (int t = 0; t < 64; ++t) {
        const int cur = t & 1;
        if (t < 63) stage(cur ^ 1, (t + 1) * 32);

        const ushort_t* Kh = Kbuf[cur][0];
        const ushort_t* Kl = Kbuf[cur][1];
        const ushort_t* Vh = Vbuf[cur][0];
        const ushort_t* Vl = Vbuf[cur][1];

        // ---- QK^T as S^T = K * Q^T (A = K fragment, m = lane&15 = key) ----
        f32x4 hh0 = zero4(), hl0 = zero4(), lh0 = zero4();
        f32x4 hh1 = zero4(), hl1 = zero4(), lh1 = zero4();
        #pragma unroll
        for (int us = 0; us < 8; ++us) {
            int off0 = kq * 256 + ((us * 32 + g * 8) ^ ((kq & 7) * 8));
            bf16x8 k0h = *reinterpret_cast<const bf16x8*>(Kh + off0);
            bf16x8 k0l = *reinterpret_cast<const bf16x8*>(Kl + off0);
            hh0 = __builtin_amdgcn_mfma_f32_16x16x32_bf16(k0h, qh[us],  hh0, 0, 0, 0);
            hl0 = __builtin_amdgcn_mfma_f32_16x16x32_bf16(k0h, qlv[us], hl0, 0, 0, 0);
            lh0 = __builtin_amdgcn_mfma_f32_16x16x32_bf16(k0l, qh[us],  lh0, 0, 0, 0);
            int off1 = off0 + 16 * 256;                     // key+16, same low bits
            bf16x8 k1h = *reinterpret_cast<const bf16x8*>(Kh + off1);
            bf16x8 k1l = *reinterpret_cast<const bf16x8*>(Kl + off1);
            hh1 = __builtin_amdgcn_mfma_f32_16x16x32_bf16(k1h, qh[us],  hh1, 0, 0, 0);
            hl1 = __builtin_amdgcn_mfma_f32_16x16x32_bf16(k1h, qlv[us], hl1, 0, 0, 0);
            lh1 = __builtin_amdgcn_mfma_f32_16x16x32_bf16(k1l, qh[us],  lh1, 0, 0, 0);
        }
        f32x4 s0 = (hh0 + hl0 + lh0) * scale;   // keys g*4+r,      q = kq
        f32x4 s1 = (hh1 + hl1 + lh1) * scale;   // keys 16+g*4+r,   q = kq

        // ---- online softmax (per q = lane&15; key-reduce = 8 in-lane + 2 shfl)
        float tm = fmaxf(fmaxf(fmaxf(s0[0], s0[1]), fmaxf(s0[2], s0[3])),
                         fmaxf(fmaxf(s1[0], s1[1]), fmaxf(s1[2], s1[3])));
        tm = fmaxf(tm, __shfl_xor(tm, 16));
        tm = fmaxf(tm, __shfl_xor(tm, 32));
        float mn = fmaxf(m_run, tm);
        float p0[4], p1[4], su = 0.f;
        #pragma unroll
        for (int r = 0; r < 4; ++r) { p0[r] = expf(s0[r] - mn); su += p0[r]; }
        #pragma unroll
        for (int r = 0; r < 4; ++r) { p1[r] = expf(s1[r] - mn); su += p1[r]; }
        su += __shfl_xor(su, 16);
        su += __shfl_xor(su, 32);
        float f = expf(m_run - mn);             // first tile: exp(-inf) = 0
        l_run = l_run * f + su;
        m_run = mn;

        // ---- write P (hi/lo) into PV-A-fragment layout [kg][q][8] ----
        ushort4 ph0, pl0, ph1, pl1;
        ph0.x = f2bf(p0[0]); pl0.x = f2bf(p0[0] - bf2f(ph0.x));
        ph0.y = f2bf(p0[1]); pl0.y = f2bf(p0[1] - bf2f(ph0.y));
        ph0.z = f2bf(p0[2]); pl0.z = f2bf(p0[2] - bf2f(ph0.z));
        ph0.w = f2bf(p0[3]); pl0.w = f2bf(p0[3] - bf2f(ph0.w));
        ph1.x = f2bf(p1[0]); pl1.x = f2bf(p1[0] - bf2f(ph1.x));
        ph1.y = f2bf(p1[1]); pl1.y = f2bf(p1[1] - bf2f(ph1.y));
        ph1.z = f2bf(p1[2]); pl1.z = f2bf(p1[2] - bf2f(ph1.z));
        ph1.w = f2bf(p1[3]); pl1.w = f2bf(p1[3] - bf2f(ph1.w));
        {
            int pw0 = ((g >> 1)) * 128 + kq * 8 + (g & 1) * 4;        // kg = 0|1
            int pw1 = (2 + (g >> 1)) * 128 + kq * 8 + (g & 1) * 4;    // kg = 2|3
            *reinterpret_cast<ushort4*>(&Pbuf[0][w][pw0]) = ph0;
            *reinterpret_cast<ushort4*>(&Pbuf[1][w][pw0]) = pl0;
            *reinterpret_cast<ushort4*>(&Pbuf[0][w][pw1]) = ph1;
            *reinterpret_cast<ushort4*>(&Pbuf[1][w][pw1]) = pl1;
        }

        // ---- rescale O (rows of C-layout are q = g*4+r) ----
        float fr0 = __shfl(f, g * 4 + 0), fr1 = __shfl(f, g * 4 + 1);
        float fr2 = __shfl(f, g * 4 + 2), fr3 = __shfl(f, g * 4 + 3);
        #pragma unroll
        for (int nt = 0; nt < 16; ++nt) {
            O[nt][0] *= fr0; O[nt][1] *= fr1; O[nt][2] *= fr2; O[nt][3] *= fr3;
        }

        // ---- PV: O += P * V (A = P frag from Pbuf, B = V frag from Vbuf) ----
        bf16x8 pa_h = *reinterpret_cast<const bf16x8*>(&Pbuf[0][w][g * 128 + kq * 8]);
        bf16x8 pa_l = *reinterpret_cast<const bf16x8*>(&Pbuf[1][w][g * 128 + kq * 8]);
        #pragma unroll
        for (int nt = 0; nt < 16; ++nt) {
            int vo = (nt * 16 + kq) * 40 + g * 8;
            bf16x8 vh = *reinterpret_cast<const bf16x8*>(Vh + vo);
            bf16x8 vl = *reinterpret_cast<const bf16x8*>(Vl + vo);
            O[nt] = __builtin_amdgcn_mfma_f32_16x16x32_bf16(pa_h, vh, O[nt], 0, 0, 0);
            O[nt] = __builtin_amdgcn_mfma_f32_16x16x32_bf16(pa_h, vl, O[nt], 0, 0, 0);
            O[nt] = __builtin_amdgcn_mfma_f32_16x16x32_bf16(pa_l, vh, O[nt], 0, 0, 0);
        }

        asm volatile("s_waitcnt vmcnt(0)" ::: "memory");
        __builtin_amdgcn_s_barrier();
    }

    // ---- epilogue: O / l, store fp32 ----
    float li0 = 1.f / __shfl(l_run, g * 4 + 0);
    float li1 = 1.f / __shfl(l_run, g * 4 + 1);
    float li2 = 1.f / __shfl(l_run, g * 4 + 2);
    float li3 = 1.f / __shfl(l_run, g * 4 + 3);
    #pragma unroll
    for (int nt = 0; nt < 16; ++nt) {
        const int col = nt * 16 + kq;
        out[(size_t)(qrow0 + g * 4 + 0) * U_ + col] = O[nt][0] * li0;
        out[(size_t)(qrow0 + g * 4 + 1) * U_ + col] = O[nt][1] * li1;
        out[(size_t)(qrow0 + g * 4 + 2) * U_ + col] = O[nt][2] * li2;
        out[(size_t)(qrow0 + g * 4 + 3) * U_ + col] = O[nt][3] * li3;
    }
}

extern "C" void kernel_launch(void* const* d_in, const int* in_sizes, int n_in,
                              void* d_out, int out_size, void* d_ws, size_t ws_size,
                              hipStream_t stream)
{
    (void)in_sizes; (void)n_in; (void)out_size; (void)ws_size;
    const float* x  = (const float*)d_in[0];
    const float* Wq = (const float*)d_in[1];
    const float* Wk = (const float*)d_in[2];
    const float* Wv = (const float*)d_in[3];
    float* out = (float*)d_out;

    ushort_t* ws = (ushort_t*)d_ws;          // 6 x 8 MiB bf16 = 48 MiB scratch
    const size_t T = (size_t)M_ * U_;        // 4,194,304 elements
    ushort_t* qhi  = ws;
    ushort_t* qlo  = ws + T;
    ushort_t* khi  = ws + 2 * T;
    ushort_t* klo  = ws + 3 * T;
    ushort_t* vthi = ws + 4 * T;             // [B][U][S]
    ushort_t* vtlo = ws + 5 * T;

    dim3 g1(M_ / 128, U_ / 64, 3);
    proj_tanh_kernel<<<g1, 256, 0, stream>>>(x, Wq, Wk, Wv,
                                             qhi, qlo, khi, klo, vthi, vtlo);

    attn_mfma_kernel<<<dim3(256), 256, 0, stream>>>(qhi, qlo, khi, klo,
                                                    vthi, vtlo, out);
}

// Round 3
// 335.951 us; speedup vs baseline: 5.0335x; 1.7204x over previous
//
#include <hip/hip_runtime.h>
#include <math.h>

#define B_ 8
#define S_ 2048
#define F_ 1024
#define U_ 256
#define M_ (B_ * S_)   // 16384 rows

typedef __attribute__((ext_vector_type(8))) short bf16x8;
typedef __attribute__((ext_vector_type(4))) float f32x4;
typedef __attribute__((ext_vector_type(16))) float f32x16;
typedef unsigned short ushort_t;

__device__ __forceinline__ unsigned short f2bf(float x) {
    unsigned u = __builtin_bit_cast(unsigned, x);
    unsigned r = (u + 0x7fffu + ((u >> 16) & 1u)) >> 16;   // RNE
    return (unsigned short)r;
}
__device__ __forceinline__ float bf2f(unsigned short b) {
    return __builtin_bit_cast(float, ((unsigned)b) << 16);
}
__device__ __forceinline__ void gload16(const void* g, void* l) {
    __builtin_amdgcn_global_load_lds(
        (const __attribute__((address_space(1))) unsigned int*)g,
        (__attribute__((address_space(3))) unsigned int*)l, 16, 0, 0);
}
__device__ __forceinline__ f32x4 zero4() {
    f32x4 v; v[0] = 0.f; v[1] = 0.f; v[2] = 0.f; v[3] = 0.f; return v;
}

// ---------------------------------------------------------------------------
// Kernel 0: repack W fp32 [1024][256] -> bf16 hi/lo, k-slice-major:
// Wp[wsel][half][kslice=k/8][n][j=k%8].  3 MB total.  Grid (128, 3) x 256.
// ---------------------------------------------------------------------------
__global__ __launch_bounds__(256) void convw_kernel(
    const float* __restrict__ Wq, const float* __restrict__ Wk,
    const float* __restrict__ Wv, ushort_t* __restrict__ Wp)
{
    const int ks   = blockIdx.x;    // 0..127
    const int wsel = blockIdx.y;    // 0..2
    const float* __restrict__ W = (wsel == 0) ? Wq : (wsel == 1) ? Wk : Wv;
    const int n = threadIdx.x;      // 0..255

    bf16x8 hv, lv;
    #pragma unroll
    for (int j = 0; j < 8; ++j) {
        float v = W[(size_t)(ks * 8 + j) * U_ + n];
        ushort_t h = f2bf(v);
        hv[j] = (short)h;
        lv[j] = (short)f2bf(v - bf2f(h));
    }
    size_t base = (size_t)wsel * 524288;   // 2*128*256*8
    *reinterpret_cast<bf16x8*>(&Wp[base + ((size_t)ks) * 2048 + n * 8]) = hv;
    *reinterpret_cast<bf16x8*>(&Wp[base + ((size_t)(128 + ks)) * 2048 + n * 8]) = lv;
}

// ---------------------------------------------------------------------------
// Kernel 1: projection GEMM via split-bf16 3-pass MFMA (32x32x16).
// Block: 64 rows x 256 cols x 1 weight; 768 blocks; 4 waves (2x2), each wave
// 32m x 128n -> acc = 4 x f32x16.  BK=32.  A staged fp32 via global_load_lds
// with XOR-pre-swizzled source; converted to bf16 hi/lo in registers.
// B staged linear (k-slice-major global layout) -> conflict-free frag reads.
// Epilogue: tanh + hi/lo split -> qhi/qlo, khi/klo, vthi/vtlo (attn layouts).
// ---------------------------------------------------------------------------
__global__ __launch_bounds__(256) void proj_mfma_kernel(
    const float* __restrict__ x,
    const ushort_t* __restrict__ Wp,
    ushort_t* __restrict__ qhi, ushort_t* __restrict__ qlo,
    ushort_t* __restrict__ khi, ushort_t* __restrict__ klo,
    ushort_t* __restrict__ vthi, ushort_t* __restrict__ vtlo)
{
    __shared__ float    As[64 * 32];          // [row][chunk swizzled], 8 KB
    __shared__ ushort_t Bs[2 * 4 * 256 * 8];  // [half][slice][n][8], 32 KB

    // XCD-chunked bijective swizzle over 768 = 8 x 96 blocks
    const int orig = blockIdx.y * 256 + blockIdx.x;
    const int swz  = (orig & 7) * 96 + (orig >> 3);
    const int wsel = swz >> 8;
    const int rb   = swz & 255;
    const int row0 = rb * 64;

    const int tid = threadIdx.x;
    const int l = tid & 63, w = tid >> 6;
    const int wy = w >> 1, wx = w & 1;
    const int m = l & 31, hi = l >> 5;

    const ushort_t* __restrict__ WpB = Wp + (size_t)wsel * 524288;

    f32x16 acc[4];
    #pragma unroll
    for (int nf = 0; nf < 4; ++nf)
        #pragma unroll
        for (int r = 0; r < 16; ++r) acc[nf][r] = 0.f;

    for (int ks = 0; ks < 32; ++ks) {
        // ---- stage A: 64 rows x 8 chunks of 16B (fp32), source-swizzled ----
        #pragma unroll
        for (int i = 0; i < 2; ++i) {
            int q = tid + i * 256;
            int r = q >> 3, c = q & 7;
            const float* src = x + (size_t)(row0 + r) * F_ + ks * 32
                               + ((c ^ (r & 7)) << 2);
            gload16(src, (char*)As + (size_t)(i * 256 + w * 64) * 16);
        }
        // ---- stage B: 2048 chunks, pure linear copy ----
        #pragma unroll
        for (int i = 0; i < 8; ++i) {
            int q = tid + i * 256;
            int gidx = (q >> 10) * 32768 + ks * 1024 + (q & 1023);
            gload16(WpB + (size_t)gidx * 8,
                    (char*)Bs + (size_t)(i * 256 + w * 64) * 16);
        }
        __syncthreads();   // drains vmcnt -> staged data visible

        #pragma unroll
        for (int g = 0; g < 2; ++g) {
            // A-frag: row = wy*32+m, k = g*16 + hi*8 + j  (fp32, swizzled chunks)
            const int r  = wy * 32 + m;
            const int cA = g * 4 + hi * 2;
            const float4 a0 = *reinterpret_cast<const float4*>(
                &As[(size_t)(r * 8 + (cA ^ (r & 7))) * 4]);
            const float4 a1 = *reinterpret_cast<const float4*>(
                &As[(size_t)(r * 8 + ((cA + 1) ^ (r & 7))) * 4]);
            const float af[8] = {a0.x, a0.y, a0.z, a0.w, a1.x, a1.y, a1.z, a1.w};
            bf16x8 ah, al;
            #pragma unroll
            for (int j = 0; j < 8; ++j) {
                ushort_t h = f2bf(af[j]);
                ah[j] = (short)h;
                al[j] = (short)f2bf(af[j] - bf2f(h));
            }
            const int sl = g * 2 + hi;
            #pragma unroll
            for (int nf = 0; nf < 4; ++nf) {
                const int nn = wx * 128 + nf * 32 + m;
                const bf16x8 bh = *reinterpret_cast<const bf16x8*>(
                    &Bs[(size_t)((0 + sl) * 256 + nn) * 8]);
                const bf16x8 bl = *reinterpret_cast<const bf16x8*>(
                    &Bs[(size_t)((4 + sl) * 256 + nn) * 8]);
                acc[nf] = __builtin_amdgcn_mfma_f32_32x32x16_bf16(ah, bh, acc[nf], 0, 0, 0);
                acc[nf] = __builtin_amdgcn_mfma_f32_32x32x16_bf16(ah, bl, acc[nf], 0, 0, 0);
                acc[nf] = __builtin_amdgcn_mfma_f32_32x32x16_bf16(al, bh, acc[nf], 0, 0, 0);
            }
        }
        __syncthreads();   // compute done -> next stage may overwrite
    }

    // ---- epilogue: tanh + split, store in attention layouts ----
    // C layout (32x32): col = lane&31, row = (reg&3) + 8*(reg>>2) + 4*(lane>>5)
    const int row_base = row0 + wy * 32;
    if (wsel < 2) {
        ushort_t* __restrict__ hp = (wsel == 0) ? qhi : khi;
        ushort_t* __restrict__ lp = (wsel == 0) ? qlo : klo;
        #pragma unroll
        for (int nf = 0; nf < 4; ++nf) {
            const int u = wx * 128 + nf * 32 + m;
            #pragma unroll
            for (int reg = 0; reg < 16; ++reg) {
                const int rl = (reg & 3) + 8 * (reg >> 2) + 4 * hi;
                float t = tanhf(acc[nf][reg]);
                ushort_t h = f2bf(t);
                size_t off = (size_t)(row_base + rl) * U_ + u;
                hp[off] = h;
                lp[off] = f2bf(t - bf2f(h));
            }
        }
    } else {
        const int b     = row0 >> 11;
        const int s_blk = (row0 & 2047) + wy * 32;
        #pragma unroll
        for (int nf = 0; nf < 4; ++nf) {
            const int u = wx * 128 + nf * 32 + m;
            #pragma unroll
            for (int rg = 0; rg < 4; ++rg) {
                ushort4 hv, lv;
                float t0 = tanhf(acc[nf][rg * 4 + 0]);
                float t1 = tanhf(acc[nf][rg * 4 + 1]);
                float t2 = tanhf(acc[nf][rg * 4 + 2]);
                float t3 = tanhf(acc[nf][rg * 4 + 3]);
                hv.x = f2bf(t0); lv.x = f2bf(t0 - bf2f(hv.x));
                hv.y = f2bf(t1); lv.y = f2bf(t1 - bf2f(hv.y));
                hv.z = f2bf(t2); lv.z = f2bf(t2 - bf2f(hv.z));
                hv.w = f2bf(t3); lv.w = f2bf(t3 - bf2f(hv.w));
                size_t off = ((size_t)b * U_ + u) * S_ + s_blk + 8 * rg + 4 * hi;
                *reinterpret_cast<ushort4*>(&vthi[off]) = hv;
                *reinterpret_cast<ushort4*>(&vtlo[off]) = lv;
            }
        }
    }
}

// ---------------------------------------------------------------------------
// Kernel 2: flash attention, split-bf16 MFMA — UNCHANGED from round 2.
// ---------------------------------------------------------------------------
__global__ __launch_bounds__(256, 1) void attn_mfma_kernel(
    const ushort_t* __restrict__ qhi, const ushort_t* __restrict__ qlo,
    const ushort_t* __restrict__ khi, const ushort_t* __restrict__ klo,
    const ushort_t* __restrict__ vthi, const ushort_t* __restrict__ vtlo,
    float* __restrict__ out)
{
    __shared__ ushort_t Kbuf[2][2][32 * 256];   // [dbuf][half][key][u] swizzled (64 KB)
    __shared__ ushort_t Vbuf[2][2][256 * 40];   // [dbuf][half][u][32+8pad]   (80 KB)
    __shared__ ushort_t Pbuf[2][4][512];        // [half][wave][kg][q][8]      (8 KB)

    const int tid = threadIdx.x;
    const int l  = tid & 63, w = tid >> 6;
    const int kq = l & 15,  g = l >> 4;

    const int logical = (blockIdx.x & 7) * 32 + (blockIdx.x >> 3);
    const int b  = logical >> 5;
    const int qb = logical & 31;
    const int qrow0 = b * S_ + qb * 64 + w * 16;

    bf16x8 qh[8], qlv[8];
    {
        const ushort_t* qbh = qhi + (size_t)(qrow0 + kq) * U_;
        const ushort_t* qbl = qlo + (size_t)(qrow0 + kq) * U_;
        #pragma unroll
        for (int us = 0; us < 8; ++us) {
            qh[us]  = *reinterpret_cast<const bf16x8*>(qbh + us * 32 + g * 8);
            qlv[us] = *reinterpret_cast<const bf16x8*>(qbl + us * 32 + g * 8);
        }
    }

    f32x4 O[16];
    #pragma unroll
    for (int nt = 0; nt < 16; ++nt) O[nt] = zero4();
    float m_run = -INFINITY, l_run = 0.f;

    auto stage = [&](int buf, int k0) {
        #pragma unroll
        for (int i = 0; i < 4; ++i) {
            int c = w * 256 + i * 64 + l;
            int key = c >> 5, uc = c & 31;
            int ucs = uc ^ (key & 7);
            size_t so = (size_t)(b * S_ + k0 + key) * U_ + ucs * 8;
            gload16(khi + so, &Kbuf[buf][0][(w * 256 + i * 64) * 8]);
            gload16(klo + so, &Kbuf[buf][1][(w * 256 + i * 64) * 8]);
        }
        #pragma unroll
        for (int i = 0; i < 5; ++i) {
            int c = w * 320 + i * 64 + l;
            int u = (c * 52429) >> 18;
            int kc = c - u * 5;
            size_t so = ((size_t)b * U_ + u) * S_ + k0 + kc * 8;
            const ushort_t* sh = (kc < 4) ? (vthi + so) : vthi;
            const ushort_t* sl = (kc < 4) ? (vtlo + so) : vtlo;
            gload16(sh, &Vbuf[buf][0][(w * 320 + i * 64) * 8]);
            gload16(sl, &Vbuf[buf][1][(w * 320 + i * 64) * 8]);
        }
    };

    stage(0, 0);
    asm volatile("s_waitcnt vmcnt(0)" ::: "memory");
    __builtin_amdgcn_s_barrier();

    const float scale = 0.03125f;   // 1/sqrt(F=1024)

    for (int t = 0; t < 64; ++t) {
        const int cur = t & 1;
        if (t < 63) stage(cur ^ 1, (t + 1) * 32);

        const ushort_t* Kh = Kbuf[cur][0];
        const ushort_t* Kl = Kbuf[cur][1];
        const ushort_t* Vh = Vbuf[cur][0];
        const ushort_t* Vl = Vbuf[cur][1];

        f32x4 hh0 = zero4(), hl0 = zero4(), lh0 = zero4();
        f32x4 hh1 = zero4(), hl1 = zero4(), lh1 = zero4();
        #pragma unroll
        for (int us = 0; us < 8; ++us) {
            int off0 = kq * 256 + ((us * 32 + g * 8) ^ ((kq & 7) * 8));
            bf16x8 k0h = *reinterpret_cast<const bf16x8*>(Kh + off0);
            bf16x8 k0l = *reinterpret_cast<const bf16x8*>(Kl + off0);
            hh0 = __builtin_amdgcn_mfma_f32_16x16x32_bf16(k0h, qh[us],  hh0, 0, 0, 0);
            hl0 = __builtin_amdgcn_mfma_f32_16x16x32_bf16(k0h, qlv[us], hl0, 0, 0, 0);
            lh0 = __builtin_amdgcn_mfma_f32_16x16x32_bf16(k0l, qh[us],  lh0, 0, 0, 0);
            int off1 = off0 + 16 * 256;
            bf16x8 k1h = *reinterpret_cast<const bf16x8*>(Kh + off1);
            bf16x8 k1l = *reinterpret_cast<const bf16x8*>(Kl + off1);
            hh1 = __builtin_amdgcn_mfma_f32_16x16x32_bf16(k1h, qh[us],  hh1, 0, 0, 0);
            hl1 = __builtin_amdgcn_mfma_f32_16x16x32_bf16(k1h, qlv[us], hl1, 0, 0, 0);
            lh1 = __builtin_amdgcn_mfma_f32_16x16x32_bf16(k1l, qh[us],  lh1, 0, 0, 0);
        }
        f32x4 s0 = (hh0 + hl0 + lh0) * scale;
        f32x4 s1 = (hh1 + hl1 + lh1) * scale;

        float tm = fmaxf(fmaxf(fmaxf(s0[0], s0[1]), fmaxf(s0[2], s0[3])),
                         fmaxf(fmaxf(s1[0], s1[1]), fmaxf(s1[2], s1[3])));
        tm = fmaxf(tm, __shfl_xor(tm, 16));
        tm = fmaxf(tm, __shfl_xor(tm, 32));
        float mn = fmaxf(m_run, tm);
        float p0[4], p1[4], su = 0.f;
        #pragma unroll
        for (int r = 0; r < 4; ++r) { p0[r] = expf(s0[r] - mn); su += p0[r]; }
        #pragma unroll
        for (int r = 0; r < 4; ++r) { p1[r] = expf(s1[r] - mn); su += p1[r]; }
        su += __shfl_xor(su, 16);
        su += __shfl_xor(su, 32);
        float f = expf(m_run - mn);
        l_run = l_run * f + su;
        m_run = mn;

        ushort4 ph0, pl0, ph1, pl1;
        ph0.x = f2bf(p0[0]); pl0.x = f2bf(p0[0] - bf2f(ph0.x));
        ph0.y = f2bf(p0[1]); pl0.y = f2bf(p0[1] - bf2f(ph0.y));
        ph0.z = f2bf(p0[2]); pl0.z = f2bf(p0[2] - bf2f(ph0.z));
        ph0.w = f2bf(p0[3]); pl0.w = f2bf(p0[3] - bf2f(ph0.w));
        ph1.x = f2bf(p1[0]); pl1.x = f2bf(p1[0] - bf2f(ph1.x));
        ph1.y = f2bf(p1[1]); pl1.y = f2bf(p1[1] - bf2f(ph1.y));
        ph1.z = f2bf(p1[2]); pl1.z = f2bf(p1[2] - bf2f(ph1.z));
        ph1.w = f2bf(p1[3]); pl1.w = f2bf(p1[3] - bf2f(ph1.w));
        {
            int pw0 = ((g >> 1)) * 128 + kq * 8 + (g & 1) * 4;
            int pw1 = (2 + (g >> 1)) * 128 + kq * 8 + (g & 1) * 4;
            *reinterpret_cast<ushort4*>(&Pbuf[0][w][pw0]) = ph0;
            *reinterpret_cast<ushort4*>(&Pbuf[1][w][pw0]) = pl0;
            *reinterpret_cast<ushort4*>(&Pbuf[0][w][pw1]) = ph1;
            *reinterpret_cast<ushort4*>(&Pbuf[1][w][pw1]) = pl1;
        }

        float fr0 = __shfl(f, g * 4 + 0), fr1 = __shfl(f, g * 4 + 1);
        float fr2 = __shfl(f, g * 4 + 2), fr3 = __shfl(f, g * 4 + 3);
        #pragma unroll
        for (int nt = 0; nt < 16; ++nt) {
            O[nt][0] *= fr0; O[nt][1] *= fr1; O[nt][2] *= fr2; O[nt][3] *= fr3;
        }

        bf16x8 pa_h = *reinterpret_cast<const bf16x8*>(&Pbuf[0][w][g * 128 + kq * 8]);
        bf16x8 pa_l = *reinterpret_cast<const bf16x8*>(&Pbuf[1][w][g * 128 + kq * 8]);
        #pragma unroll
        for (int nt = 0; nt < 16; ++nt) {
            int vo = (nt * 16 + kq) * 40 + g * 8;
            bf16x8 vh = *reinterpret_cast<const bf16x8*>(Vh + vo);
            bf16x8 vl = *reinterpret_cast<const bf16x8*>(Vl + vo);
            O[nt] = __builtin_amdgcn_mfma_f32_16x16x32_bf16(pa_h, vh, O[nt], 0, 0, 0);
            O[nt] = __builtin_amdgcn_mfma_f32_16x16x32_bf16(pa_h, vl, O[nt], 0, 0, 0);
            O[nt] = __builtin_amdgcn_mfma_f32_16x16x32_bf16(pa_l, vh, O[nt], 0, 0, 0);
        }

        asm volatile("s_waitcnt vmcnt(0)" ::: "memory");
        __builtin_amdgcn_s_barrier();
    }

    float li0 = 1.f / __shfl(l_run, g * 4 + 0);
    float li1 = 1.f / __shfl(l_run, g * 4 + 1);
    float li2 = 1.f / __shfl(l_run, g * 4 + 2);
    float li3 = 1.f / __shfl(l_run, g * 4 + 3);
    #pragma unroll
    for (int nt = 0; nt < 16; ++nt) {
        const int col = nt * 16 + kq;
        out[(size_t)(qrow0 + g * 4 + 0) * U_ + col] = O[nt][0] * li0;
        out[(size_t)(qrow0 + g * 4 + 1) * U_ + col] = O[nt][1] * li1;
        out[(size_t)(qrow0 + g * 4 + 2) * U_ + col] = O[nt][2] * li2;
        out[(size_t)(qrow0 + g * 4 + 3) * U_ + col] = O[nt][3] * li3;
    }
}

extern "C" void kernel_launch(void* const* d_in, const int* in_sizes, int n_in,
                              void* d_out, int out_size, void* d_ws, size_t ws_size,
                              hipStream_t stream)
{
    (void)in_sizes; (void)n_in; (void)out_size; (void)ws_size;
    const float* x  = (const float*)d_in[0];
    const float* Wq = (const float*)d_in[1];
    const float* Wk = (const float*)d_in[2];
    const float* Wv = (const float*)d_in[3];
    float* out = (float*)d_out;

    ushort_t* ws = (ushort_t*)d_ws;          // 48 MiB QKV + 3 MiB Wp
    const size_t T = (size_t)M_ * U_;        // 4,194,304 elements
    ushort_t* qhi  = ws;
    ushort_t* qlo  = ws + T;
    ushort_t* khi  = ws + 2 * T;
    ushort_t* klo  = ws + 3 * T;
    ushort_t* vthi = ws + 4 * T;             // [B][U][S]
    ushort_t* vtlo = ws + 5 * T;
    ushort_t* Wp   = ws + 6 * T;             // [3][2][128][256][8]

    convw_kernel<<<dim3(128, 3), 256, 0, stream>>>(Wq, Wk, Wv, Wp);

    proj_mfma_kernel<<<dim3(256, 3), 256, 0, stream>>>(
        x, Wp, qhi, qlo, khi, klo, vthi, vtlo);

    attn_mfma_kernel<<<dim3(256), 256, 0, stream>>>(qhi, qlo, khi, klo,
                                                    vthi, vtlo, out);
}

// Round 4
// 219.044 us; speedup vs baseline: 7.7199x; 1.5337x over previous
//
#include <hip/hip_runtime.h>
#include <math.h>

#define B_ 8
#define S_ 2048
#define F_ 1024
#define U_ 256
#define M_ (B_ * S_)   // 16384 rows

typedef __attribute__((ext_vector_type(8))) short bf16x8;
typedef __attribute__((ext_vector_type(4))) float f32x4;
typedef __attribute__((ext_vector_type(16))) float f32x16;
typedef unsigned short ushort_t;

__device__ __forceinline__ unsigned short f2bf(float x) {
    unsigned u = __builtin_bit_cast(unsigned, x);
    unsigned r = (u + 0x7fffu + ((u >> 16) & 1u)) >> 16;   // RNE
    return (unsigned short)r;
}
__device__ __forceinline__ float bf2f(unsigned short b) {
    return __builtin_bit_cast(float, ((unsigned)b) << 16);
}
__device__ __forceinline__ void gload16(const void* g, void* l) {
    __builtin_amdgcn_global_load_lds(
        (const __attribute__((address_space(1))) unsigned int*)g,
        (__attribute__((address_space(3))) unsigned int*)l, 16, 0, 0);
}
__device__ __forceinline__ f32x4 zero4() {
    f32x4 v; v[0] = 0.f; v[1] = 0.f; v[2] = 0.f; v[3] = 0.f; return v;
}

// ---------------------------------------------------------------------------
// Kernel 0: repack W fp32 [1024][256] -> bf16 hi/lo, k-slice-major:
// Wp[wsel][half][kslice=k/8][n][j=k%8].  3 MB total.  Grid (128, 3) x 256.
// (Projection GEMM remains 3-pass split-bf16 -> needs both halves.)
// ---------------------------------------------------------------------------
__global__ __launch_bounds__(256) void convw_kernel(
    const float* __restrict__ Wq, const float* __restrict__ Wk,
    const float* __restrict__ Wv, ushort_t* __restrict__ Wp)
{
    const int ks   = blockIdx.x;    // 0..127
    const int wsel = blockIdx.y;    // 0..2
    const float* __restrict__ W = (wsel == 0) ? Wq : (wsel == 1) ? Wk : Wv;
    const int n = threadIdx.x;      // 0..255

    bf16x8 hv, lv;
    #pragma unroll
    for (int j = 0; j < 8; ++j) {
        float v = W[(size_t)(ks * 8 + j) * U_ + n];
        ushort_t h = f2bf(v);
        hv[j] = (short)h;
        lv[j] = (short)f2bf(v - bf2f(h));
    }
    size_t base = (size_t)wsel * 524288;   // 2*128*256*8
    *reinterpret_cast<bf16x8*>(&Wp[base + ((size_t)ks) * 2048 + n * 8]) = hv;
    *reinterpret_cast<bf16x8*>(&Wp[base + ((size_t)(128 + ks)) * 2048 + n * 8]) = lv;
}

// ---------------------------------------------------------------------------
// Kernel 1: projection GEMM via split-bf16 3-pass MFMA (32x32x16).
// Identical GEMM core to round 3 (verified). Epilogue now emits HI-ONLY
// bf16 outputs (attention is plain-bf16 now): qh [M][U], kh [M][U],
// vth [B][U][S].
// ---------------------------------------------------------------------------
__global__ __launch_bounds__(256) void proj_mfma_kernel(
    const float* __restrict__ x,
    const ushort_t* __restrict__ Wp,
    ushort_t* __restrict__ qh_g, ushort_t* __restrict__ kh_g,
    ushort_t* __restrict__ vth_g)
{
    __shared__ float    As[64 * 32];          // [row][chunk swizzled], 8 KB
    __shared__ ushort_t Bs[2 * 4 * 256 * 8];  // [half][slice][n][8], 32 KB

    // XCD-chunked bijective swizzle over 768 = 8 x 96 blocks
    const int orig = blockIdx.y * 256 + blockIdx.x;
    const int swz  = (orig & 7) * 96 + (orig >> 3);
    const int wsel = swz >> 8;
    const int rb   = swz & 255;
    const int row0 = rb * 64;

    const int tid = threadIdx.x;
    const int l = tid & 63, w = tid >> 6;
    const int wy = w >> 1, wx = w & 1;
    const int m = l & 31, hi = l >> 5;

    const ushort_t* __restrict__ WpB = Wp + (size_t)wsel * 524288;

    f32x16 acc[4];
    #pragma unroll
    for (int nf = 0; nf < 4; ++nf)
        #pragma unroll
        for (int r = 0; r < 16; ++r) acc[nf][r] = 0.f;

    for (int ks = 0; ks < 32; ++ks) {
        // ---- stage A: 64 rows x 8 chunks of 16B (fp32), source-swizzled ----
        #pragma unroll
        for (int i = 0; i < 2; ++i) {
            int q = tid + i * 256;
            int r = q >> 3, c = q & 7;
            const float* src = x + (size_t)(row0 + r) * F_ + ks * 32
                               + ((c ^ (r & 7)) << 2);
            gload16(src, (char*)As + (size_t)(i * 256 + w * 64) * 16);
        }
        // ---- stage B: 2048 chunks, pure linear copy ----
        #pragma unroll
        for (int i = 0; i < 8; ++i) {
            int q = tid + i * 256;
            int gidx = (q >> 10) * 32768 + ks * 1024 + (q & 1023);
            gload16(WpB + (size_t)gidx * 8,
                    (char*)Bs + (size_t)(i * 256 + w * 64) * 16);
        }
        __syncthreads();

        #pragma unroll
        for (int g = 0; g < 2; ++g) {
            const int r  = wy * 32 + m;
            const int cA = g * 4 + hi * 2;
            const float4 a0 = *reinterpret_cast<const float4*>(
                &As[(size_t)(r * 8 + (cA ^ (r & 7))) * 4]);
            const float4 a1 = *reinterpret_cast<const float4*>(
                &As[(size_t)(r * 8 + ((cA + 1) ^ (r & 7))) * 4]);
            const float af[8] = {a0.x, a0.y, a0.z, a0.w, a1.x, a1.y, a1.z, a1.w};
            bf16x8 ah, al;
            #pragma unroll
            for (int j = 0; j < 8; ++j) {
                ushort_t h = f2bf(af[j]);
                ah[j] = (short)h;
                al[j] = (short)f2bf(af[j] - bf2f(h));
            }
            const int sl = g * 2 + hi;
            #pragma unroll
            for (int nf = 0; nf < 4; ++nf) {
                const int nn = wx * 128 + nf * 32 + m;
                const bf16x8 bh = *reinterpret_cast<const bf16x8*>(
                    &Bs[(size_t)((0 + sl) * 256 + nn) * 8]);
                const bf16x8 bl = *reinterpret_cast<const bf16x8*>(
                    &Bs[(size_t)((4 + sl) * 256 + nn) * 8]);
                acc[nf] = __builtin_amdgcn_mfma_f32_32x32x16_bf16(ah, bh, acc[nf], 0, 0, 0);
                acc[nf] = __builtin_amdgcn_mfma_f32_32x32x16_bf16(ah, bl, acc[nf], 0, 0, 0);
                acc[nf] = __builtin_amdgcn_mfma_f32_32x32x16_bf16(al, bh, acc[nf], 0, 0, 0);
            }
        }
        __syncthreads();
    }

    // ---- epilogue: tanh, round to bf16, store (hi only) ----
    // C layout (32x32): col = lane&31, row = (reg&3) + 8*(reg>>2) + 4*(lane>>5)
    const int row_base = row0 + wy * 32;
    if (wsel < 2) {
        ushort_t* __restrict__ hp = (wsel == 0) ? qh_g : kh_g;
        #pragma unroll
        for (int nf = 0; nf < 4; ++nf) {
            const int u = wx * 128 + nf * 32 + m;
            #pragma unroll
            for (int reg = 0; reg < 16; ++reg) {
                const int rl = (reg & 3) + 8 * (reg >> 2) + 4 * hi;
                hp[(size_t)(row_base + rl) * U_ + u] = f2bf(tanhf(acc[nf][reg]));
            }
        }
    } else {
        const int b     = row0 >> 11;
        const int s_blk = (row0 & 2047) + wy * 32;
        #pragma unroll
        for (int nf = 0; nf < 4; ++nf) {
            const int u = wx * 128 + nf * 32 + m;
            #pragma unroll
            for (int rg = 0; rg < 4; ++rg) {
                ushort4 hv;
                hv.x = f2bf(tanhf(acc[nf][rg * 4 + 0]));
                hv.y = f2bf(tanhf(acc[nf][rg * 4 + 1]));
                hv.z = f2bf(tanhf(acc[nf][rg * 4 + 2]));
                hv.w = f2bf(tanhf(acc[nf][rg * 4 + 3]));
                size_t off = ((size_t)b * U_ + u) * S_ + s_blk + 8 * rg + 4 * hi;
                *reinterpret_cast<ushort4*>(&vth_g[off]) = hv;
            }
        }
    }
}

// ---------------------------------------------------------------------------
// Kernel 2: flash attention, plain bf16 MFMA (1-pass).
// LDS 76 KB -> 2 blocks/CU (2 waves/SIMD). Same fragment maps as round 3.
// Softmax denominator accumulated from bf16-ROUNDED P for exact
// normalization of the PV weights.
// ---------------------------------------------------------------------------
__global__ __launch_bounds__(256, 2) void attn_mfma_kernel(
    const ushort_t* __restrict__ qh_g,
    const ushort_t* __restrict__ kh_g,
    const ushort_t* __restrict__ vth_g,
    float* __restrict__ out)
{
    __shared__ ushort_t Kbuf[2][32 * 256];   // [dbuf][key][u] swizzled (32 KB)
    __shared__ ushort_t Vbuf[2][256 * 40];   // [dbuf][u][32+8pad]     (40 KB)
    __shared__ ushort_t Pbuf[4][512];        // [wave][kg][q][8]        (4 KB)

    const int tid = threadIdx.x;
    const int l  = tid & 63, w = tid >> 6;
    const int kq = l & 15,  g = l >> 4;

    // XCD swizzle: batch b lands wholly on XCD b (K/V L2-resident)
    const int logical = (blockIdx.x & 7) * 32 + (blockIdx.x >> 3);
    const int b  = logical >> 5;
    const int qb = logical & 31;
    const int qrow0 = b * S_ + qb * 64 + w * 16;

    // preload Q fragments (B-operand: n = lane&15 -> q, k = u = g*8+j)
    bf16x8 qh[8];
    {
        const ushort_t* qbh = qh_g + (size_t)(qrow0 + kq) * U_;
        #pragma unroll
        for (int us = 0; us < 8; ++us)
            qh[us] = *reinterpret_cast<const bf16x8*>(qbh + us * 32 + g * 8);
    }

    f32x4 O[16];
    #pragma unroll
    for (int nt = 0; nt < 16; ++nt) O[nt] = zero4();
    float m_run = -INFINITY, l_run = 0.f;

    auto stage = [&](int buf, int k0) {
        // K: 1024 16B-chunks; wave w: chunks w*256 + i*64 + lane
        #pragma unroll
        for (int i = 0; i < 4; ++i) {
            int c = w * 256 + i * 64 + l;
            int key = c >> 5, uc = c & 31;
            int ucs = uc ^ (key & 7);                       // pre-swizzled source
            size_t so = (size_t)(b * S_ + k0 + key) * U_ + ucs * 8;
            gload16(kh_g + so, &Kbuf[buf][(w * 256 + i * 64) * 8]);
        }
        // V: 1280 chunks (rows of 5: 4 data + 1 pad)
        #pragma unroll
        for (int i = 0; i < 5; ++i) {
            int c = w * 320 + i * 64 + l;
            int u = (c * 52429) >> 18;                      // c / 5
            int kc = c - u * 5;
            size_t so = ((size_t)b * U_ + u) * S_ + k0 + kc * 8;
            const ushort_t* sh = (kc < 4) ? (vth_g + so) : vth_g;
            gload16(sh, &Vbuf[buf][(w * 320 + i * 64) * 8]);
        }
    };

    stage(0, 0);
    asm volatile("s_waitcnt vmcnt(0)" ::: "memory");
    __builtin_amdgcn_s_barrier();

    const float scale = 0.03125f;   // 1/sqrt(F=1024)

    for (int t = 0; t < 64; ++t) {
        const int cur = t & 1;
        if (t < 63) stage(cur ^ 1, (t + 1) * 32);

        const ushort_t* Kh = Kbuf[cur];
        const ushort_t* Vh = Vbuf[cur];

        // ---- QK^T as S^T = K * Q^T (A = K fragment, m = lane&15 = key) ----
        f32x4 hh0 = zero4(), hh1 = zero4();
        #pragma unroll
        for (int us = 0; us < 8; ++us) {
            int off0 = kq * 256 + ((us * 32 + g * 8) ^ ((kq & 7) * 8));
            bf16x8 k0h = *reinterpret_cast<const bf16x8*>(Kh + off0);
            hh0 = __builtin_amdgcn_mfma_f32_16x16x32_bf16(k0h, qh[us], hh0, 0, 0, 0);
            int off1 = off0 + 16 * 256;                     // key+16
            bf16x8 k1h = *reinterpret_cast<const bf16x8*>(Kh + off1);
            hh1 = __builtin_amdgcn_mfma_f32_16x16x32_bf16(k1h, qh[us], hh1, 0, 0, 0);
        }
        f32x4 s0 = hh0 * scale;   // keys g*4+r,    q = kq
        f32x4 s1 = hh1 * scale;   // keys 16+g*4+r, q = kq

        // ---- online softmax (per q = lane&15) ----
        float tm = fmaxf(fmaxf(fmaxf(s0[0], s0[1]), fmaxf(s0[2], s0[3])),
                         fmaxf(fmaxf(s1[0], s1[1]), fmaxf(s1[2], s1[3])));
        tm = fmaxf(tm, __shfl_xor(tm, 16));
        tm = fmaxf(tm, __shfl_xor(tm, 32));
        float mn = fmaxf(m_run, tm);
        ushort_t ph0[4], ph1[4];
        float su = 0.f;
        #pragma unroll
        for (int r = 0; r < 4; ++r) {
            ph0[r] = f2bf(expf(s0[r] - mn)); su += bf2f(ph0[r]);
        }
        #pragma unroll
        for (int r = 0; r < 4; ++r) {
            ph1[r] = f2bf(expf(s1[r] - mn)); su += bf2f(ph1[r]);
        }
        su += __shfl_xor(su, 16);
        su += __shfl_xor(su, 32);
        float f = expf(m_run - mn);             // first tile: exp(-inf) = 0
        l_run = l_run * f + su;
        m_run = mn;

        // ---- write P into PV-A-fragment layout [kg][q][8] ----
        {
            ushort4 a, c;
            a.x = ph0[0]; a.y = ph0[1]; a.z = ph0[2]; a.w = ph0[3];
            c.x = ph1[0]; c.y = ph1[1]; c.z = ph1[2]; c.w = ph1[3];
            int pw0 = ((g >> 1)) * 128 + kq * 8 + (g & 1) * 4;        // kg 0|1
            int pw1 = (2 + (g >> 1)) * 128 + kq * 8 + (g & 1) * 4;    // kg 2|3
            *reinterpret_cast<ushort4*>(&Pbuf[w][pw0]) = a;
            *reinterpret_cast<ushort4*>(&Pbuf[w][pw1]) = c;
        }

        // ---- rescale O (rows of C-layout are q = g*4+r) ----
        float fr0 = __shfl(f, g * 4 + 0), fr1 = __shfl(f, g * 4 + 1);
        float fr2 = __shfl(f, g * 4 + 2), fr3 = __shfl(f, g * 4 + 3);
        #pragma unroll
        for (int nt = 0; nt < 16; ++nt) {
            O[nt][0] *= fr0; O[nt][1] *= fr1; O[nt][2] *= fr2; O[nt][3] *= fr3;
        }

        // ---- PV: O += P * V ----
        bf16x8 pa_h = *reinterpret_cast<const bf16x8*>(&Pbuf[w][g * 128 + kq * 8]);
        #pragma unroll
        for (int nt = 0; nt < 16; ++nt) {
            int vo = (nt * 16 + kq) * 40 + g * 8;
            bf16x8 vh = *reinterpret_cast<const bf16x8*>(Vh + vo);
            O[nt] = __builtin_amdgcn_mfma_f32_16x16x32_bf16(pa_h, vh, O[nt], 0, 0, 0);
        }

        asm volatile("s_waitcnt vmcnt(0)" ::: "memory");
        __builtin_amdgcn_s_barrier();
    }

    // ---- epilogue: O / l, store fp32 ----
    float li0 = 1.f / __shfl(l_run, g * 4 + 0);
    float li1 = 1.f / __shfl(l_run, g * 4 + 1);
    float li2 = 1.f / __shfl(l_run, g * 4 + 2);
    float li3 = 1.f / __shfl(l_run, g * 4 + 3);
    #pragma unroll
    for (int nt = 0; nt < 16; ++nt) {
        const int col = nt * 16 + kq;
        out[(size_t)(qrow0 + g * 4 + 0) * U_ + col] = O[nt][0] * li0;
        out[(size_t)(qrow0 + g * 4 + 1) * U_ + col] = O[nt][1] * li1;
        out[(size_t)(qrow0 + g * 4 + 2) * U_ + col] = O[nt][2] * li2;
        out[(size_t)(qrow0 + g * 4 + 3) * U_ + col] = O[nt][3] * li3;
    }
}

extern "C" void kernel_launch(void* const* d_in, const int* in_sizes, int n_in,
                              void* d_out, int out_size, void* d_ws, size_t ws_size,
                              hipStream_t stream)
{
    (void)in_sizes; (void)n_in; (void)out_size; (void)ws_size;
    const float* x  = (const float*)d_in[0];
    const float* Wq = (const float*)d_in[1];
    const float* Wk = (const float*)d_in[2];
    const float* Wv = (const float*)d_in[3];
    float* out = (float*)d_out;

    ushort_t* ws = (ushort_t*)d_ws;          // 24 MiB QKV(hi) + 3 MiB Wp
    const size_t T = (size_t)M_ * U_;        // 4,194,304 elements
    ushort_t* qh_g  = ws;
    ushort_t* kh_g  = ws + T;
    ushort_t* vth_g = ws + 2 * T;            // [B][U][S]
    ushort_t* Wp    = ws + 3 * T;            // [3][2][128][256][8]

    convw_kernel<<<dim3(128, 3), 256, 0, stream>>>(Wq, Wk, Wv, Wp);

    proj_mfma_kernel<<<dim3(256, 3), 256, 0, stream>>>(
        x, Wp, qh_g, kh_g, vth_g);

    attn_mfma_kernel<<<dim3(256), 256, 0, stream>>>(qh_g, kh_g, vth_g, out);
}

// Round 5
// 192.828 us; speedup vs baseline: 8.7695x; 1.1360x over previous
//
#include <hip/hip_runtime.h>
#include <math.h>

#define B_ 8
#define S_ 2048
#define F_ 1024
#define U_ 256
#define M_ (B_ * S_)   // 16384 rows

typedef __attribute__((ext_vector_type(8))) short bf16x8;
typedef __attribute__((ext_vector_type(4))) float f32x4;
typedef __attribute__((ext_vector_type(16))) float f32x16;
typedef unsigned short ushort_t;

__device__ __forceinline__ unsigned short f2bf(float x) {
    unsigned u = __builtin_bit_cast(unsigned, x);
    unsigned r = (u + 0x7fffu + ((u >> 16) & 1u)) >> 16;   // RNE
    return (unsigned short)r;
}
__device__ __forceinline__ float bf2f(unsigned short b) {
    return __builtin_bit_cast(float, ((unsigned)b) << 16);
}
__device__ __forceinline__ void gload16(const void* g, void* l) {
    __builtin_amdgcn_global_load_lds(
        (const __attribute__((address_space(1))) unsigned int*)g,
        (__attribute__((address_space(3))) unsigned int*)l, 16, 0, 0);
}
__device__ __forceinline__ f32x4 zero4() {
    f32x4 v; v[0] = 0.f; v[1] = 0.f; v[2] = 0.f; v[3] = 0.f; return v;
}

// ---------------------------------------------------------------------------
// Kernel 0: repack W fp32 [1024][256] -> bf16 hi/lo, k-slice-major:
// Wp[wsel][half][kslice=k/8][n][j=k%8].  3 MB total.  Grid (128, 3) x 256.
// ---------------------------------------------------------------------------
__global__ __launch_bounds__(256) void convw_kernel(
    const float* __restrict__ Wq, const float* __restrict__ Wk,
    const float* __restrict__ Wv, ushort_t* __restrict__ Wp)
{
    const int ks   = blockIdx.x;    // 0..127
    const int wsel = blockIdx.y;    // 0..2
    const float* __restrict__ W = (wsel == 0) ? Wq : (wsel == 1) ? Wk : Wv;
    const int n = threadIdx.x;      // 0..255

    bf16x8 hv, lv;
    #pragma unroll
    for (int j = 0; j < 8; ++j) {
        float v = W[(size_t)(ks * 8 + j) * U_ + n];
        ushort_t h = f2bf(v);
        hv[j] = (short)h;
        lv[j] = (short)f2bf(v - bf2f(h));
    }
    size_t base = (size_t)wsel * 524288;   // 2*128*256*8
    *reinterpret_cast<bf16x8*>(&Wp[base + ((size_t)ks) * 2048 + n * 8]) = hv;
    *reinterpret_cast<bf16x8*>(&Wp[base + ((size_t)(128 + ks)) * 2048 + n * 8]) = lv;
}

// ---------------------------------------------------------------------------
// Kernel 1: projection GEMM, split-bf16 3-pass MFMA (32x32x16).
// NEW: M-tile 128 (M_rep=2 per wave) -> B-fragment reads per MFMA halved.
// Block: 128 rows x 256 cols; 384 blocks (2/CU); 4 waves (2x2), each wave
// 64m x 128n -> acc = 2 x 4 x f32x16.  BK=32.  LDS 48 KB.
// ---------------------------------------------------------------------------
__global__ __launch_bounds__(256, 2) void proj_mfma_kernel(
    const float* __restrict__ x,
    const ushort_t* __restrict__ Wp,
    ushort_t* __restrict__ qh_g, ushort_t* __restrict__ kh_g,
    ushort_t* __restrict__ vth_g)
{
    __shared__ float    As[128 * 32];         // [row][chunk swizzled], 16 KB
    __shared__ ushort_t Bs[2 * 4 * 256 * 8];  // [half][slice][n][8],   32 KB

    // XCD-chunked bijective swizzle over 384 = 8 x 48 blocks
    const int orig = blockIdx.y * 128 + blockIdx.x;
    const int swz  = (orig & 7) * 48 + (orig >> 3);
    const int wsel = swz >> 7;        // 128 row-tiles per weight
    const int rb   = swz & 127;
    const int row0 = rb * 128;

    const int tid = threadIdx.x;
    const int l = tid & 63, w = tid >> 6;
    const int wy = w >> 1, wx = w & 1;
    const int m = l & 31, hi = l >> 5;

    const ushort_t* __restrict__ WpB = Wp + (size_t)wsel * 524288;

    f32x16 acc[2][4];
    #pragma unroll
    for (int mr = 0; mr < 2; ++mr)
        #pragma unroll
        for (int nf = 0; nf < 4; ++nf)
            #pragma unroll
            for (int r = 0; r < 16; ++r) acc[mr][nf][r] = 0.f;

    for (int ks = 0; ks < 32; ++ks) {
        // ---- stage A: 128 rows x 8 chunks of 16B (fp32), source-swizzled ----
        #pragma unroll
        for (int i = 0; i < 4; ++i) {
            int q = tid + i * 256;
            int r = q >> 3, c = q & 7;
            const float* src = x + (size_t)(row0 + r) * F_ + ks * 32
                               + ((c ^ (r & 7)) << 2);
            gload16(src, (char*)As + (size_t)(i * 256 + w * 64) * 16);
        }
        // ---- stage B: 2048 chunks, pure linear copy ----
        #pragma unroll
        for (int i = 0; i < 8; ++i) {
            int q = tid + i * 256;
            int gidx = (q >> 10) * 32768 + ks * 1024 + (q & 1023);
            gload16(WpB + (size_t)gidx * 8,
                    (char*)Bs + (size_t)(i * 256 + w * 64) * 16);
        }
        __syncthreads();

        #pragma unroll
        for (int g = 0; g < 2; ++g) {
            // A-frags: row = wy*64 + mr*32 + m, k = g*16 + hi*8 + j
            bf16x8 ah[2], al[2];
            #pragma unroll
            for (int mr = 0; mr < 2; ++mr) {
                const int r  = wy * 64 + mr * 32 + m;
                const int cA = g * 4 + hi * 2;
                const float4 a0 = *reinterpret_cast<const float4*>(
                    &As[(size_t)(r * 8 + (cA ^ (r & 7))) * 4]);
                const float4 a1 = *reinterpret_cast<const float4*>(
                    &As[(size_t)(r * 8 + ((cA + 1) ^ (r & 7))) * 4]);
                const float af[8] = {a0.x, a0.y, a0.z, a0.w,
                                     a1.x, a1.y, a1.z, a1.w};
                #pragma unroll
                for (int j = 0; j < 8; ++j) {
                    ushort_t h = f2bf(af[j]);
                    ah[mr][j] = (short)h;
                    al[mr][j] = (short)f2bf(af[j] - bf2f(h));
                }
            }
            const int sl = g * 2 + hi;
            #pragma unroll
            for (int nf = 0; nf < 4; ++nf) {
                const int nn = wx * 128 + nf * 32 + m;
                const bf16x8 bh = *reinterpret_cast<const bf16x8*>(
                    &Bs[(size_t)((0 + sl) * 256 + nn) * 8]);
                const bf16x8 bl = *reinterpret_cast<const bf16x8*>(
                    &Bs[(size_t)((4 + sl) * 256 + nn) * 8]);
                #pragma unroll
                for (int mr = 0; mr < 2; ++mr) {
                    acc[mr][nf] = __builtin_amdgcn_mfma_f32_32x32x16_bf16(ah[mr], bh, acc[mr][nf], 0, 0, 0);
                    acc[mr][nf] = __builtin_amdgcn_mfma_f32_32x32x16_bf16(ah[mr], bl, acc[mr][nf], 0, 0, 0);
                    acc[mr][nf] = __builtin_amdgcn_mfma_f32_32x32x16_bf16(al[mr], bh, acc[mr][nf], 0, 0, 0);
                }
            }
        }
        __syncthreads();
    }

    // ---- epilogue: tanh, round to bf16, store (hi only) ----
    // C layout (32x32): col = lane&31, row = (reg&3) + 8*(reg>>2) + 4*(lane>>5)
    #pragma unroll
    for (int mr = 0; mr < 2; ++mr) {
        const int row_base = row0 + wy * 64 + mr * 32;
        if (wsel < 2) {
            ushort_t* __restrict__ hp = (wsel == 0) ? qh_g : kh_g;
            #pragma unroll
            for (int nf = 0; nf < 4; ++nf) {
                const int u = wx * 128 + nf * 32 + m;
                #pragma unroll
                for (int reg = 0; reg < 16; ++reg) {
                    const int rl = (reg & 3) + 8 * (reg >> 2) + 4 * hi;
                    hp[(size_t)(row_base + rl) * U_ + u] =
                        f2bf(tanhf(acc[mr][nf][reg]));
                }
            }
        } else {
            const int b     = row0 >> 11;    // 128-row tiles never straddle batches
            const int s_blk = (row0 & 2047) + wy * 64 + mr * 32;
            #pragma unroll
            for (int nf = 0; nf < 4; ++nf) {
                const int u = wx * 128 + nf * 32 + m;
                #pragma unroll
                for (int rg = 0; rg < 4; ++rg) {
                    ushort4 hv;
                    hv.x = f2bf(tanhf(acc[mr][nf][rg * 4 + 0]));
                    hv.y = f2bf(tanhf(acc[mr][nf][rg * 4 + 1]));
                    hv.z = f2bf(tanhf(acc[mr][nf][rg * 4 + 2]));
                    hv.w = f2bf(tanhf(acc[mr][nf][rg * 4 + 3]));
                    size_t off = ((size_t)b * U_ + u) * S_ + s_blk + 8 * rg + 4 * hi;
                    *reinterpret_cast<ushort4*>(&vth_g[off]) = hv;
                }
            }
        }
    }
}

// ---------------------------------------------------------------------------
// Kernel 2: flash attention, plain bf16 MFMA, SPLIT-K x2.
// 512 blocks = 8 batches x 32 q-tiles x 2 key-halves; 2 blocks/CU -> 2
// waves/SIMD. Each block: 64 q-rows x 1024 keys (32 tiles of 32), writes
// UNNORMALIZED O (kh=0 -> d_out, kh=1 -> ws) + per-row (m, l).
// ---------------------------------------------------------------------------
__global__ __launch_bounds__(256, 2) void attn_mfma_kernel(
    const ushort_t* __restrict__ qh_g,
    const ushort_t* __restrict__ kh_g,
    const ushort_t* __restrict__ vth_g,
    float* __restrict__ O0, float* __restrict__ O1,
    float* __restrict__ ml)
{
    __shared__ ushort_t Kbuf[2][32 * 256];   // [dbuf][key][u] swizzled (32 KB)
    __shared__ ushort_t Vbuf[2][256 * 40];   // [dbuf][u][32+8pad]     (40 KB)
    __shared__ ushort_t Pbuf[4][512];        // [wave][kg][q][8]        (4 KB)

    const int tid = threadIdx.x;
    const int l  = tid & 63, w = tid >> 6;
    const int kq = l & 15,  g = l >> 4;

    // XCD swizzle: each XCD owns one batch (64 blocks: 32 q-tiles x 2 halves)
    const int logical = (blockIdx.x & 7) * 64 + (blockIdx.x >> 3);
    const int b     = logical >> 6;
    const int qb    = (logical >> 1) & 31;
    const int khalf = logical & 1;
    const int qrow0 = b * S_ + qb * 64 + w * 16;
    const int kb0   = khalf * 1024;           // key offset within batch

    // preload Q fragments (B-operand: n = lane&15 -> q, k = u = g*8+j)
    bf16x8 qh[8];
    {
        const ushort_t* qbh = qh_g + (size_t)(qrow0 + kq) * U_;
        #pragma unroll
        for (int us = 0; us < 8; ++us)
            qh[us] = *reinterpret_cast<const bf16x8*>(qbh + us * 32 + g * 8);
    }

    f32x4 O[16];
    #pragma unroll
    for (int nt = 0; nt < 16; ++nt) O[nt] = zero4();
    float m_run = -INFINITY, l_run = 0.f;

    auto stage = [&](int buf, int k0) {
        #pragma unroll
        for (int i = 0; i < 4; ++i) {
            int c = w * 256 + i * 64 + l;
            int key = c >> 5, uc = c & 31;
            int ucs = uc ^ (key & 7);                       // pre-swizzled source
            size_t so = (size_t)(b * S_ + k0 + key) * U_ + ucs * 8;
            gload16(kh_g + so, &Kbuf[buf][(w * 256 + i * 64) * 8]);
        }
        #pragma unroll
        for (int i = 0; i < 5; ++i) {
            int c = w * 320 + i * 64 + l;
            int u = (c * 52429) >> 18;                      // c / 5
            int kc = c - u * 5;
            size_t so = ((size_t)b * U_ + u) * S_ + k0 + kc * 8;
            const ushort_t* sh = (kc < 4) ? (vth_g + so) : vth_g;
            gload16(sh, &Vbuf[buf][(w * 320 + i * 64) * 8]);
        }
    };

    stage(0, kb0);
    asm volatile("s_waitcnt vmcnt(0)" ::: "memory");
    __builtin_amdgcn_s_barrier();

    const float scale = 0.03125f;   // 1/sqrt(F=1024)

    for (int t = 0; t < 32; ++t) {
        const int cur = t & 1;
        if (t < 31) stage(cur ^ 1, kb0 + (t + 1) * 32);

        const ushort_t* Kh = Kbuf[cur];
        const ushort_t* Vh = Vbuf[cur];

        // ---- QK^T as S^T = K * Q^T ----
        f32x4 hh0 = zero4(), hh1 = zero4();
        #pragma unroll
        for (int us = 0; us < 8; ++us) {
            int off0 = kq * 256 + ((us * 32 + g * 8) ^ ((kq & 7) * 8));
            bf16x8 k0h = *reinterpret_cast<const bf16x8*>(Kh + off0);
            hh0 = __builtin_amdgcn_mfma_f32_16x16x32_bf16(k0h, qh[us], hh0, 0, 0, 0);
            int off1 = off0 + 16 * 256;                     // key+16
            bf16x8 k1h = *reinterpret_cast<const bf16x8*>(Kh + off1);
            hh1 = __builtin_amdgcn_mfma_f32_16x16x32_bf16(k1h, qh[us], hh1, 0, 0, 0);
        }
        f32x4 s0 = hh0 * scale;   // keys g*4+r,    q = kq
        f32x4 s1 = hh1 * scale;   // keys 16+g*4+r, q = kq

        // ---- online softmax (per q = lane&15) ----
        float tm = fmaxf(fmaxf(fmaxf(s0[0], s0[1]), fmaxf(s0[2], s0[3])),
                         fmaxf(fmaxf(s1[0], s1[1]), fmaxf(s1[2], s1[3])));
        tm = fmaxf(tm, __shfl_xor(tm, 16));
        tm = fmaxf(tm, __shfl_xor(tm, 32));
        float mn = fmaxf(m_run, tm);
        ushort_t ph0[4], ph1[4];
        float su = 0.f;
        #pragma unroll
        for (int r = 0; r < 4; ++r) {
            ph0[r] = f2bf(expf(s0[r] - mn)); su += bf2f(ph0[r]);
        }
        #pragma unroll
        for (int r = 0; r < 4; ++r) {
            ph1[r] = f2bf(expf(s1[r] - mn)); su += bf2f(ph1[r]);
        }
        su += __shfl_xor(su, 16);
        su += __shfl_xor(su, 32);
        float f = expf(m_run - mn);             // first tile: exp(-inf) = 0
        l_run = l_run * f + su;
        m_run = mn;

        // ---- write P into PV-A-fragment layout [kg][q][8] ----
        {
            ushort4 a, c;
            a.x = ph0[0]; a.y = ph0[1]; a.z = ph0[2]; a.w = ph0[3];
            c.x = ph1[0]; c.y = ph1[1]; c.z = ph1[2]; c.w = ph1[3];
            int pw0 = ((g >> 1)) * 128 + kq * 8 + (g & 1) * 4;        // kg 0|1
            int pw1 = (2 + (g >> 1)) * 128 + kq * 8 + (g & 1) * 4;    // kg 2|3
            *reinterpret_cast<ushort4*>(&Pbuf[w][pw0]) = a;
            *reinterpret_cast<ushort4*>(&Pbuf[w][pw1]) = c;
        }

        // ---- rescale O (rows of C-layout are q = g*4+r) ----
        float fr0 = __shfl(f, g * 4 + 0), fr1 = __shfl(f, g * 4 + 1);
        float fr2 = __shfl(f, g * 4 + 2), fr3 = __shfl(f, g * 4 + 3);
        #pragma unroll
        for (int nt = 0; nt < 16; ++nt) {
            O[nt][0] *= fr0; O[nt][1] *= fr1; O[nt][2] *= fr2; O[nt][3] *= fr3;
        }

        // ---- PV: O += P * V ----
        bf16x8 pa_h = *reinterpret_cast<const bf16x8*>(&Pbuf[w][g * 128 + kq * 8]);
        #pragma unroll
        for (int nt = 0; nt < 16; ++nt) {
            int vo = (nt * 16 + kq) * 40 + g * 8;
            bf16x8 vh = *reinterpret_cast<const bf16x8*>(Vh + vo);
            O[nt] = __builtin_amdgcn_mfma_f32_16x16x32_bf16(pa_h, vh, O[nt], 0, 0, 0);
        }

        asm volatile("s_waitcnt vmcnt(0)" ::: "memory");
        __builtin_amdgcn_s_barrier();
    }

    // ---- epilogue: store UNNORMALIZED O + (m, l) per row ----
    float* __restrict__ Op = khalf ? O1 : O0;
    #pragma unroll
    for (int nt = 0; nt < 16; ++nt) {
        const int col = nt * 16 + kq;
        Op[(size_t)(qrow0 + g * 4 + 0) * U_ + col] = O[nt][0];
        Op[(size_t)(qrow0 + g * 4 + 1) * U_ + col] = O[nt][1];
        Op[(size_t)(qrow0 + g * 4 + 2) * U_ + col] = O[nt][2];
        Op[(size_t)(qrow0 + g * 4 + 3) * U_ + col] = O[nt][3];
    }
    if (g == 0) {   // lanes 0..15: one per q-row of this wave
        ml[((size_t)khalf * M_ + qrow0 + kq) * 2 + 0] = m_run;
        ml[((size_t)khalf * M_ + qrow0 + kq) * 2 + 1] = l_run;
    }
}

// ---------------------------------------------------------------------------
// Kernel 3: merge the two split-K partials.
// out = (e^{m0-M} O0 + e^{m1-M} O1) / (e^{m0-M} l0 + e^{m1-M} l1).
// Grid 4096 x 256: block = 4 rows, thread = one float4.
// ---------------------------------------------------------------------------
__global__ __launch_bounds__(256) void merge_kernel(
    const float* __restrict__ O1, const float* __restrict__ ml,
    float* __restrict__ out)
{
    const int tid = threadIdx.x;
    const int row = blockIdx.x * 4 + (tid >> 6);
    const int c   = (tid & 63) * 4;

    const float m0 = ml[(size_t)row * 2 + 0];
    const float l0 = ml[(size_t)row * 2 + 1];
    const float m1 = ml[((size_t)M_ + row) * 2 + 0];
    const float l1 = ml[((size_t)M_ + row) * 2 + 1];
    const float Mx = fmaxf(m0, m1);
    float a0 = expf(m0 - Mx), a1 = expf(m1 - Mx);
    const float inv = 1.f / (a0 * l0 + a1 * l1);
    a0 *= inv; a1 *= inv;

    const size_t off = (size_t)row * U_ + c;
    const float4 o0 = *reinterpret_cast<const float4*>(out + off);
    const float4 o1 = *reinterpret_cast<const float4*>(O1 + off);
    float4 r;
    r.x = o0.x * a0 + o1.x * a1;
    r.y = o0.y * a0 + o1.y * a1;
    r.z = o0.z * a0 + o1.z * a1;
    r.w = o0.w * a0 + o1.w * a1;
    *reinterpret_cast<float4*>(out + off) = r;
}

extern "C" void kernel_launch(void* const* d_in, const int* in_sizes, int n_in,
                              void* d_out, int out_size, void* d_ws, size_t ws_size,
                              hipStream_t stream)
{
    (void)in_sizes; (void)n_in; (void)out_size; (void)ws_size;
    const float* x  = (const float*)d_in[0];
    const float* Wq = (const float*)d_in[1];
    const float* Wk = (const float*)d_in[2];
    const float* Wv = (const float*)d_in[3];
    float* out = (float*)d_out;

    ushort_t* ws = (ushort_t*)d_ws;
    const size_t T = (size_t)M_ * U_;        // 4,194,304 elements
    ushort_t* qh_g  = ws;                    //  8 MiB
    ushort_t* kh_g  = ws + T;                //  8 MiB
    ushort_t* vth_g = ws + 2 * T;            //  8 MiB  [B][U][S]
    ushort_t* Wp    = ws + 3 * T;            //  3 MiB  [3][2][128][256][8]
    float*    O1    = (float*)(ws + 3 * T + 1572864);   // 16.8 MiB partial
    float*    ml    = O1 + T;                // 0.26 MiB [2][M][2]

    convw_kernel<<<dim3(128, 3), 256, 0, stream>>>(Wq, Wk, Wv, Wp);

    proj_mfma_kernel<<<dim3(128, 3), 256, 0, stream>>>(
        x, Wp, qh_g, kh_g, vth_g);

    attn_mfma_kernel<<<dim3(512), 256, 0, stream>>>(
        qh_g, kh_g, vth_g, out, O1, ml);

    merge_kernel<<<dim3(M_ / 4), 256, 0, stream>>>(O1, ml, out);
}